// Round 6
// baseline (209.915 us; speedup 1.0000x reference)
//
#include <hip/hip_runtime.h>

#define VOCABN 64
#define EMBN   128
#define HDIM   256
#define NUMIN  7
#define BN     64
#define SN     2048
#define TWOH   512
#define SEG    16
#define SEGLEN 128

__device__ __forceinline__ float rcpf(float x){ return __builtin_amdgcn_rcpf(x); }

__device__ __forceinline__ float fast_exp2(float x){
#if __has_builtin(__builtin_amdgcn_exp2f)
    return __builtin_amdgcn_exp2f(x);
#else
    return exp2f(x);
#endif
}

// v_pk_fma_f32 with src0 broadcast from LO half (result.lo and .hi both use src0.lo)
__device__ __forceinline__ float2 pk_fma_blo(float2 a, float2 b, float2 c){
    float2 d;
    asm("v_pk_fma_f32 %0, %1, %2, %3 op_sel_hi:[0,1,1]" : "=v"(d) : "v"(a), "v"(b), "v"(c));
    return d;
}
// v_pk_fma_f32 with src0 broadcast from HI half
__device__ __forceinline__ float2 pk_fma_bhi(float2 a, float2 b, float2 c){
    float2 d;
    asm("v_pk_fma_f32 %0, %1, %2, %3 op_sel:[1,0,0] op_sel_hi:[1,1,1]" : "=v"(d) : "v"(a), "v"(b), "v"(c));
    return d;
}
__device__ __forceinline__ float2 pk_mul(float2 a, float2 b){
    float2 d;
    asm("v_pk_mul_f32 %0, %1, %2" : "=v"(d) : "v"(a), "v"(b));
    return d;
}

// 64-lane sum via DPP; result valid in lane 63.
__device__ __forceinline__ float waveRedDpp(float x){
    x += __int_as_float(__builtin_amdgcn_update_dpp(0, __float_as_int(x), 0x111, 0xf, 0xf, false)); // row_shr:1
    x += __int_as_float(__builtin_amdgcn_update_dpp(0, __float_as_int(x), 0x112, 0xf, 0xf, false)); // row_shr:2
    x += __int_as_float(__builtin_amdgcn_update_dpp(0, __float_as_int(x), 0x114, 0xf, 0xf, false)); // row_shr:4
    x += __int_as_float(__builtin_amdgcn_update_dpp(0, __float_as_int(x), 0x118, 0xf, 0xf, false)); // row_shr:8
    x += __int_as_float(__builtin_amdgcn_update_dpp(0, __float_as_int(x), 0x142, 0xa, 0xf, false)); // row_bcast:15
    x += __int_as_float(__builtin_amdgcn_update_dpp(0, __float_as_int(x), 0x143, 0xc, 0xf, false)); // row_bcast:31
    return x;
}

// ---------------- K1: fold emb/bias/num path into INTERLEAVED tables ----------------
// T[(dir,v,j)] = float2(z-col j, f-col j+256); U[(dir,i,j)] likewise.
__global__ __launch_bounds__(512) void k1_tables(
    const float* __restrict__ emb, const float* __restrict__ num_W, const float* __restrict__ num_b,
    const float* __restrict__ Wf, const float* __restrict__ bf,
    const float* __restrict__ Wb, const float* __restrict__ bb,
    float* __restrict__ T, float* __restrict__ U)
{
    const int blk = blockIdx.x;
    const int c = threadIdx.x;
    const int j = c & (HDIM-1);
    const int g = c >> 8;               // 0 -> z gate, 1 -> f gate
    const int col = g*HDIM + j;
    if (blk < 2*VOCABN) {
        const int dir = blk & 1, v = blk >> 1;
        const float* W    = dir ? Wb : Wf;
        const float* bias = dir ? bb : bf;
        float acc = bias[col];
        const float* e = emb + (size_t)v*EMBN;
        #pragma unroll 8
        for (int k=0;k<EMBN;++k) acc = fmaf(e[k], W[(size_t)k*768 + col], acc);
        #pragma unroll
        for (int m=0;m<4;++m)    acc = fmaf(num_b[m], W[(size_t)(EMBN+m)*768 + col], acc);
        T[(((size_t)dir*VOCABN + v)*HDIM + j)*2 + g] = acc;
    } else {
        const int dir = blk - 2*VOCABN;
        const float* W = dir ? Wb : Wf;
        #pragma unroll
        for (int i=0;i<NUMIN;++i){
            float acc = 0.f;
            #pragma unroll
            for (int m=0;m<4;++m) acc = fmaf(num_W[i*4+m], W[(size_t)(EMBN+m)*768 + col], acc);
            U[(((size_t)dir*8 + i)*HDIM + j)*2 + g] = acc;
        }
    }
}

// ---------------- K2: segmented fo-pool scan (packed math, 3-trans gates, deep prefetch) ----------------
// MODE 0: per-segment affine coefficients a=prod(f), c=scan from 0.
// MODE 1: scan from hstart, per-wave score partials via DPP reduce.
// MODE 2: scan from hstart, ctx += w[s]*h.
// Block=(b,dir,seg), thread j owns channel j; (zp,fp) packed in a VGPR pair.
// T rows prefetched 3 steps ahead (register ring) via LDS evb[] byte-offsets.
template<int MODE>
__global__ __launch_bounds__(256) void k2_scan(
    const float* __restrict__ X, const float* __restrict__ T, const float* __restrict__ U,
    const float* __restrict__ Mu, const float* __restrict__ w,
    const float* __restrict__ hstart,
    float* __restrict__ aArr, float* __restrict__ cArr,
    float* __restrict__ swp, float* __restrict__ ctxp)
{
    const int bid = blockIdx.x;
    const int seg = bid & (SEG-1);
    const int dir = (bid >> 4) & 1;
    const int b   = bid >> 5;
    const int j   = threadIdx.x;
    const size_t segIdx = ((size_t)(b*2+dir)*SEG + seg)*HDIM + j;

    const float2* Td2 = (const float2*)T + (size_t)dir*VOCABN*HDIM;
    const float2* Ud2 = (const float2*)U + (size_t)dir*8*HDIM;
    float2 u0 = Ud2[0*HDIM+j], u1 = Ud2[1*HDIM+j], u2 = Ud2[2*HDIM+j],
           u3 = Ud2[3*HDIM+j], u4 = Ud2[4*HDIM+j], u5 = Ud2[5*HDIM+j],
           u6 = Ud2[6*HDIM+j];
    const float mu = (MODE==1) ? Mu[dir*HDIM + j] : 0.f;
    const float* Xb = X + (size_t)b*SN*8;

    __shared__ float4 xlds[SEGLEN+3][2];   // raw X row: [ev n0 n1 n2][n3 n4 n5 n6], +3 pad rows
    __shared__ int    evb[SEGLEN+3];       // T-row byte offsets
    __shared__ float  wch[SEGLEN];

    const int sBeg = seg*SEGLEN;
    {   // staging: thread j stores one contiguous 16B chunk -> conflict-free
        const int r = j >> 1, half = j & 1;
        const int spos = sBeg + r;
        const int gp = dir ? (SN-1-spos) : spos;
        float4 v4 = *(const float4*)(Xb + (size_t)gp*8 + half*4);
        xlds[r][half] = v4;
        if (half==0) evb[r] = (int)v4.x * (HDIM*8);
        if (j < 6) { // pad rows SEGLEN..SEGLEN+2 (clamped to sequence end)
            const int pr = SEGLEN + (j>>1);
            int sp2 = sBeg + pr; if (sp2 > SN-1) sp2 = SN-1;
            const int gp2 = dir ? (SN-1-sp2) : sp2;
            float4 w4 = *(const float4*)(Xb + (size_t)gp2*8 + half*4);
            xlds[pr][half] = w4;
            if (half==0) evb[pr] = (int)w4.x * (HDIM*8);
        }
        if (MODE==2 && j < SEGLEN) wch[j] = w[(size_t)b*SN + sBeg + j];
    }
    __syncthreads();

    float h = (MODE==0) ? 0.f : hstart[segIdx];
    float aacc = 1.f;
    float ctxacc = 0.f;
    float* swpp = swp + (size_t)(b*8 + dir*4 + (j>>6))*SN + sBeg;

    const char* Tb = (const char*)Td2;
    const int j8 = j*8;
    float4 A  = xlds[0][0];
    float4 B4 = xlds[0][1];
    float2 tc0 = *(const float2*)(Tb + (evb[0] + j8));
    float2 tc1 = *(const float2*)(Tb + (evb[1] + j8));
    float2 tc2 = *(const float2*)(Tb + (evb[2] + j8));
    const float2 ecst = make_float2(2.8853900818f, 1.4426950409f); // 2*log2(e), log2(e)

    #pragma unroll 8
    for (int si=0; si<SEGLEN; ++si){
        const float4 An = xlds[si+1][0];
        const float4 Bn = xlds[si+1][1];
        const float2 t3 = *(const float2*)(Tb + (evb[si+3] + j8));

        float2 zf = tc0;
        zf = pk_fma_bhi(make_float2(A.x ,A.y ), u0, zf);  // n0 = A.y
        zf = pk_fma_blo(make_float2(A.z ,A.w ), u1, zf);  // n1 = A.z
        zf = pk_fma_bhi(make_float2(A.z ,A.w ), u2, zf);  // n2 = A.w
        zf = pk_fma_blo(make_float2(B4.x,B4.y), u3, zf);  // n3
        zf = pk_fma_bhi(make_float2(B4.x,B4.y), u4, zf);  // n4
        zf = pk_fma_blo(make_float2(B4.z,B4.w), u5, zf);  // n5
        zf = pk_fma_bhi(make_float2(B4.z,B4.w), u6, zf);  // n6

        // gates via one reciprocal:
        //   z = (e2z-1)/(e2z+1), f = ef/(1+ef)
        //   h' = f*h + (1-f)*z = (ef*h*(1+e2z) + (e2z-1)) / ((1+ef)(1+e2z))
        const float2 ex  = pk_mul(zf, ecst);     // (2*log2e*zp, log2e*fp)
        const float e2z = fast_exp2(ex.x);
        const float ef  = fast_exp2(ex.y);
        const float a2  = 1.f + e2z;
        const float a1  = 1.f + ef;
        const float r_  = rcpf(a1 * a2);
        const float num = fmaf(ef * h, a2, e2z - 1.f);
        h = num * r_;

        if (MODE==0){
            aacc *= ef * a2 * r_;               // f = ef/(1+ef)
        } else if (MODE==1){
            float pr = waveRedDpp(h*mu);
            if ((j & 63) == 63) swpp[si] = pr;
        } else {
            ctxacc = fmaf(wch[si], h, ctxacc);
        }
        A = An; B4 = Bn; tc0 = tc1; tc1 = tc2; tc2 = t3;
    }
    if (MODE==0){ aArr[segIdx] = aacc; cArr[segIdx] = h; }
    if (MODE==2){ ctxp[segIdx] = ctxacc; }
}

// ---------------- compose: hstart[seg] = h; h = a*h + c ----------------
__global__ __launch_bounds__(256) void k_compose(const float* __restrict__ aArr, const float* __restrict__ cArr,
                                                 float* __restrict__ hstart)
{
    const int bd = blockIdx.x;   // b*2 + dir
    const int j  = threadIdx.x;
    float h = 0.f;
    #pragma unroll
    for (int seg=0; seg<SEG; ++seg){
        const size_t idx = ((size_t)bd*SEG + seg)*HDIM + j;
        hstart[idx] = h;
        h = fmaf(aArr[idx], h, cArr[idx]);
    }
}

// ---------------- K3: softmax over S per batch ----------------
__global__ __launch_bounds__(256) void k3_softmax(const float* __restrict__ swp, float* __restrict__ w)
{
    __shared__ float sc[SN];
    __shared__ float red[4];
    const int b = blockIdx.x, t = threadIdx.x;
    for (int s=t; s<SN; s+=256){
        float acc = 0.f;
        #pragma unroll
        for (int r=0;r<8;++r) acc += swp[((size_t)b*8 + r)*SN + s];
        sc[s] = acc;
    }
    __syncthreads();
    float m = -3.4e38f;
    for (int s=t; s<SN; s+=256) m = fmaxf(m, sc[s]);
    #pragma unroll
    for (int o=32;o;o>>=1) m = fmaxf(m, __shfl_xor(m,o,64));
    if ((t&63)==0) red[t>>6] = m;
    __syncthreads();
    m = fmaxf(fmaxf(red[0],red[1]), fmaxf(red[2],red[3]));
    float zs = 0.f;
    for (int s=t; s<SN; s+=256){
        float e = __expf(sc[s]-m);
        sc[s] = e;
        zs += e;
    }
    #pragma unroll
    for (int o=32;o;o>>=1) zs += __shfl_xor(zs,o,64);
    __syncthreads();
    if ((t&63)==0) red[t>>6] = zs;
    __syncthreads();
    zs = red[0]+red[1]+red[2]+red[3];
    float invz = rcpf(zs);
    for (int s=t; s<SN; s+=256) w[(size_t)b*SN + s] = sc[s]*invz;
}

// ---------------- K5: out[b] = (sum_seg ctxp) . out_W + out_b ----------------
__global__ __launch_bounds__(512) void k5_out(const float* __restrict__ ctxp, const float* __restrict__ out_W,
                                              const float* __restrict__ out_b, float* __restrict__ out)
{
    __shared__ float red[8];
    const int b = blockIdx.x, c = threadIdx.x;
    const int dir = c >> 8, j = c & (HDIM-1);
    float acc = 0.f;
    #pragma unroll
    for (int seg=0; seg<SEG; ++seg)
        acc += ctxp[((size_t)(b*2+dir)*SEG + seg)*HDIM + j];
    float p = acc * out_W[c];
    #pragma unroll
    for (int o=32;o;o>>=1) p += __shfl_xor(p,o,64);
    if ((c&63)==0) red[c>>6] = p;
    __syncthreads();
    if (c==0){
        float t = 0.f;
        #pragma unroll
        for (int r=0;r<8;++r) t += red[r];
        out[b] = t + out_b[0];
    }
}

extern "C" void kernel_launch(void* const* d_in, const int* in_sizes, int n_in,
                              void* d_out, int out_size, void* d_ws, size_t ws_size,
                              hipStream_t stream)
{
    const float* X     = (const float*)d_in[0];
    const float* emb   = (const float*)d_in[1];
    const float* num_W = (const float*)d_in[2];
    const float* num_b = (const float*)d_in[3];
    const float* Wf    = (const float*)d_in[4];
    const float* bf    = (const float*)d_in[5];
    const float* Wb    = (const float*)d_in[6];
    const float* bb    = (const float*)d_in[7];
    const float* Mu    = (const float*)d_in[8];
    const float* out_W = (const float*)d_in[9];
    const float* out_b = (const float*)d_in[10];
    float* out = (float*)d_out;

    float* ws = (float*)d_ws;
    size_t off = 0;
    float* swp   = ws + off; off += (size_t)BN*8*SN;           // 4 MB
    float* w     = ws + off; off += (size_t)BN*SN;             // 0.5 MB
    float* T     = ws + off; off += (size_t)2*VOCABN*TWOH;     // interleaved
    float* U     = ws + off; off += (size_t)2*8*TWOH;          // interleaved
    float* aArr  = ws + off; off += (size_t)BN*2*SEG*HDIM;     // 2 MB
    float* cArr  = ws + off; off += (size_t)BN*2*SEG*HDIM;     // 2 MB
    float* hstart= ws + off; off += (size_t)BN*2*SEG*HDIM;     // 2 MB
    float* ctxp  = ws + off; off += (size_t)BN*2*SEG*HDIM;     // 2 MB

    hipLaunchKernelGGL(k1_tables,   dim3(2*VOCABN+2),  dim3(512), 0, stream,
                       emb, num_W, num_b, Wf, bf, Wb, bb, T, U);
    hipLaunchKernelGGL(k2_scan<0>,  dim3(BN*2*SEG),    dim3(256), 0, stream,
                       X, T, U, Mu, w, hstart, aArr, cArr, swp, ctxp);
    hipLaunchKernelGGL(k_compose,   dim3(BN*2),        dim3(256), 0, stream,
                       aArr, cArr, hstart);
    hipLaunchKernelGGL(k2_scan<1>,  dim3(BN*2*SEG),    dim3(256), 0, stream,
                       X, T, U, Mu, w, hstart, aArr, cArr, swp, ctxp);
    hipLaunchKernelGGL(k3_softmax,  dim3(BN),          dim3(256), 0, stream,
                       swp, w);
    hipLaunchKernelGGL(k2_scan<2>,  dim3(BN*2*SEG),    dim3(256), 0, stream,
                       X, T, U, Mu, w, hstart, aArr, cArr, swp, ctxp);
    hipLaunchKernelGGL(k5_out,      dim3(BN),          dim3(512), 0, stream,
                       ctxp, out_W, out_b, out);
}